// Round 4
// baseline (202.142 us; speedup 1.0000x reference)
//
#include <hip/hip_runtime.h>

// DynamicRouting: grouped 1x1 conv (einsum bgihw,gfi->bgfhw) + 3-iter routing.
// B=16, G=8, FI=FO=64, HW=4096. Fully fused: con never touches HBM.
//
// R8: depth-3 x prefetch. R7 measured 78.5 us with everything idle (HBM 13.5%,
// Mfma 4%, VALU 12%, occ 20%): latency-bound. Occupancy is register-capped at
// 2 waves/SIMD (128 AGPR acc + 88 VGPR), so latency must be hidden by per-wave
// prefetch depth, and R7's depth-2 gave only ~1 step of effective lead (X(g)
// issued end of step g-2, waited at step g) -> step period ~ full (page-thrash
// inflated) load latency. R8: 3 x-buffers, per-step issue order
// [WLOAD(g+2), XSTAGE(g+3)] so retiring W(g) never drains younger X tiles
// (FIFO: ..., W(g-1), X(g), W(g), X(g+1), W(g+1), X(g+2)); steady wait
// vmcnt(12) leaves {X(g+1), W(g+1), X(g+2)} in flight -> X lead = 3 steps,
// W lead = 2. Tail: vmcnt(8), vmcnt(0). LDS = 3x16K x + 2x16K w = 80 KB ->
// still exactly 2 blocks/CU (163840 B = full 160 KiB). WCONV/LGKM0/barrier
// pairing/XGRP/routing epilogue byte-identical to R7 (passed, absmax 0.125).

typedef __attribute__((ext_vector_type(8))) _Float16 half8;
typedef __attribute__((ext_vector_type(4))) float f32x4;

#define NG   8
#define NFI  64
#define NFO  64
#define HW   4096

__device__ __forceinline__ float sigmoidf_fast(float v) {
    float e = __builtin_amdgcn_exp2f(-1.44269504088896f * v);
    return __builtin_amdgcn_rcpf(1.0f + e);
}

// ---- fused conv + routing: LDS-staged x AND w, depth-3 x pipeline ----
__global__ __launch_bounds__(256, 2)
void routing_kernel(const float* __restrict__ x,
                    const float* __restrict__ w,
                    const float* __restrict__ bias,
                    float* __restrict__ out) {
    const int tid  = threadIdx.x;
    const int b    = blockIdx.x >> 6;          // batch
    const int p0   = (blockIdx.x & 63) << 6;   // pixel tile base
    const int lane = tid & 63;
    const int wv   = tid >> 6;                 // wave -> 16-px slice / w t-row
    const int pl   = lane & 15;                // MFMA n-lane (pixel)
    const int q    = lane >> 4;                // k-octet select / C row group
    const int pw   = wv * 16 + pl;             // pixel within tile

    // triple-buffered x tiles (64ch x 64px fp32 = 16 KB), double-buffered w
    __shared__ float    xlds[3][64 * 64];
    __shared__ _Float16 wlds[2][16 * 512];

    const float* xbase = x + (size_t)b * (NG * NFI) * HW;

    // w source for this thread's fragments: row t=wv*16+pl, k-octet q*8 (+32
    // for the upper k-half). Group g adds g*4096 floats. 16 B aligned.
    const float* wsrc = w + (size_t)(wv * 16 + pl) * NFI + q * 8;

    // per-lane X-stage source pointers. Stage instr c: wave writes LDS floats
    // [(wv*16 + c*4)*64, +256) linearly (lane i -> +i*4 floats). Lane covers
    // ch = wv*16 + c*4 + (lane>>4), slots pl*4..pl*4+3. Rotation swizzle:
    // LDS[ch*64 + s] holds pixel p = (s - 8*(ch>>3)) & 63, so the global
    // source is pre-rotated; runs of 4 slots map to contiguous 4-px runs.
#define MKXS(c) \
    const int   ch##c = wv * 16 + (c) * 4 + q; \
    const float* xs##c = xbase + (size_t)ch##c * HW + p0 + ((pl * 4 - 8 * (ch##c >> 3)) & 63);
    MKXS(0) MKXS(1) MKXS(2) MKXS(3)
#undef MKXS

    // b-frag read bases (floats, within a 16 KB x tile):
    //   b0 row ch=q*8+j  : rot=8q    -> slot=(pw+8q)&63,    + j*64
    //   b1 row ch=32+q*8+j: rot=32+8q -> slot=(pw+8q+32)&63, + j*64
    // bank = (pl + 8q + 16wv) mod 32 -> exactly 2 lanes/bank (free).
    const int rb0 = q * 512 + ((pw + 8 * q) & 63);
    const int rb1 = 2048 + q * 512 + ((pw + 8 * q + 32) & 63);

    f32x4 acc[NG][4];
    #pragma unroll
    for (int g = 0; g < NG; ++g)
        #pragma unroll
        for (int t = 0; t < 4; ++t)
            acc[g][t] = (f32x4){0.f, 0.f, 0.f, 0.f};

#define CB    asm volatile("" ::: "memory")
#define BAR   __builtin_amdgcn_s_barrier()
#define SB0   __builtin_amdgcn_sched_barrier(0)
#define WAITV(N) asm volatile("s_waitcnt vmcnt(" #N ")" ::: "memory")
#define LGKM0 asm volatile("s_waitcnt lgkmcnt(0)" ::: "memory")

    // load group G's raw fp32 weight octets for this thread (4 x dwordx4)
#define WLOAD(G, NM)                                                          \
    NM##a = *(const f32x4*)(wsrc + (size_t)(G) * 4096);                       \
    NM##b = *(const f32x4*)(wsrc + (size_t)(G) * 4096 + 4);                   \
    NM##c = *(const f32x4*)(wsrc + (size_t)(G) * 4096 + 32);                  \
    NM##d = *(const f32x4*)(wsrc + (size_t)(G) * 4096 + 36);

    // convert to h/l fp16 split (bit-identical to old wconv) and write the
    // fragment-ordered rows t=wv, c=0..3 into wlds[(G)&1]. Each ds_write_b128
    // has lanes at consecutive 16 B -> conflict-free.
#define WCONV(G, NM)                                                          \
    {                                                                         \
        half8 h0_, h1_, l0_, l1_;                                             \
        _Pragma("unroll")                                                     \
        for (int j = 0; j < 4; ++j) {                                         \
            float f0 = NM##a[j], f1 = NM##b[j], f2 = NM##c[j], f3 = NM##d[j]; \
            _Float16 e0 = (_Float16)f0, e1 = (_Float16)f1;                    \
            _Float16 e2 = (_Float16)f2, e3 = (_Float16)f3;                    \
            h0_[j] = e0; h0_[j + 4] = e1;                                     \
            h1_[j] = e2; h1_[j + 4] = e3;                                     \
            l0_[j]     = (_Float16)(f0 - (float)e0);                          \
            l0_[j + 4] = (_Float16)(f1 - (float)e1);                          \
            l1_[j]     = (_Float16)(f2 - (float)e2);                          \
            l1_[j + 4] = (_Float16)(f3 - (float)e3);                          \
        }                                                                     \
        _Float16* wd_ = &wlds[(G) & 1][0] + (wv * 4) * 512 + lane * 8;        \
        *(half8*)(wd_)        = h0_;                                          \
        *(half8*)(wd_ + 512)  = h1_;                                          \
        *(half8*)(wd_ + 1024) = l0_;                                          \
        *(half8*)(wd_ + 1536) = l1_;                                          \
    }

    // stage group G's 16 KB x tile: 4 x 1 KB global_load_lds per wave
#define XSTAGE(G, BUF)                                                        \
    {                                                                         \
        const size_t go_ = (size_t)(G) * 64 * HW;                             \
        float* xd_ = &xlds[BUF][0] + (wv * 16) * 64;                          \
        __builtin_amdgcn_global_load_lds(                                     \
            (const __attribute__((address_space(1))) void*)(xs0 + go_),       \
            (__attribute__((address_space(3))) void*)(xd_), 16, 0, 0);        \
        __builtin_amdgcn_global_load_lds(                                     \
            (const __attribute__((address_space(1))) void*)(xs1 + go_),       \
            (__attribute__((address_space(3))) void*)(xd_ + 256), 16, 0, 0);  \
        __builtin_amdgcn_global_load_lds(                                     \
            (const __attribute__((address_space(1))) void*)(xs2 + go_),       \
            (__attribute__((address_space(3))) void*)(xd_ + 512), 16, 0, 0);  \
        __builtin_amdgcn_global_load_lds(                                     \
            (const __attribute__((address_space(1))) void*)(xs3 + go_),       \
            (__attribute__((address_space(3))) void*)(xd_ + 768), 16, 0, 0);  \
    }

    // consume group G from x buffer BUF / w buffer G&1
#define XGRP(G, BUF)                                                         \
    {                                                                        \
        const float* xr0_ = &xlds[BUF][0] + rb0;                             \
        const float* xr1_ = &xlds[BUF][0] + rb1;                             \
        half8 b0, b1;                                                        \
        b0[0] = (_Float16)xr0_[0 * 64]; b0[1] = (_Float16)xr0_[1 * 64];      \
        b0[2] = (_Float16)xr0_[2 * 64]; b0[3] = (_Float16)xr0_[3 * 64];      \
        b0[4] = (_Float16)xr0_[4 * 64]; b0[5] = (_Float16)xr0_[5 * 64];      \
        b0[6] = (_Float16)xr0_[6 * 64]; b0[7] = (_Float16)xr0_[7 * 64];      \
        b1[0] = (_Float16)xr1_[0 * 64]; b1[1] = (_Float16)xr1_[1 * 64];      \
        b1[2] = (_Float16)xr1_[2 * 64]; b1[3] = (_Float16)xr1_[3 * 64];      \
        b1[4] = (_Float16)xr1_[4 * 64]; b1[5] = (_Float16)xr1_[5 * 64];      \
        b1[6] = (_Float16)xr1_[6 * 64]; b1[7] = (_Float16)xr1_[7 * 64];      \
        const _Float16* wg_ = &wlds[(G) & 1][0] + lane * 8;                  \
        _Pragma("unroll")                                                    \
        for (int t = 0; t < 4; ++t) {                                        \
            const _Float16* wp_ = wg_ + (size_t)t * 2048;                    \
            half8 a0h = *(const half8*)(wp_);                                \
            half8 a1h = *(const half8*)(wp_ + 512);                          \
            half8 a0l = *(const half8*)(wp_ + 1024);                         \
            half8 a1l = *(const half8*)(wp_ + 1536);                         \
            acc[G][t] = __builtin_amdgcn_mfma_f32_16x16x32_f16(a0h, b0, acc[G][t], 0, 0, 0); \
            acc[G][t] = __builtin_amdgcn_mfma_f32_16x16x32_f16(a1h, b1, acc[G][t], 0, 0, 0); \
            acc[G][t] = __builtin_amdgcn_mfma_f32_16x16x32_f16(a0l, b0, acc[G][t], 0, 0, 0); \
            acc[G][t] = __builtin_amdgcn_mfma_f32_16x16x32_f16(a1l, b1, acc[G][t], 0, 0, 0); \
        }                                                                    \
    }

    f32x4 Waa, Wab, Wac, Wad;   // w fp32 regs, even groups
    f32x4 Wba, Wbb, Wbc, Wbd;   // w fp32 regs, odd groups

    // Prologue FIFO: W0(4) X0(4) W1(4) X1(4) X2(4) -- 20 vmem instrs in flight
    WLOAD(0, Wa) CB; XSTAGE(0, 0); CB;
    WLOAD(1, Wb) CB; XSTAGE(1, 1); CB;
    XSTAGE(2, 2); CB;

    // Steady step g: [vmcnt(12): retire X(g),W(g); keep {X(g+1),W(g+1),X(g+2)}
    // in flight -> X lead 3 steps, W lead 2] [convert+ds_write w(g)]
    // [lgkmcnt(0)] [barrier: all waves' X(g)/w(g) visible] [compute g]
    // [barrier: bufs free] [issue W(g+2) then X(g+3) into freed x buffer].
    WAITV(12); WCONV(0, Wa) LGKM0; BAR; SB0; XGRP(0, 0); BAR; WLOAD(2, Wa) CB; XSTAGE(3, 0); CB;
    WAITV(12); WCONV(1, Wb) LGKM0; BAR; SB0; XGRP(1, 1); BAR; WLOAD(3, Wb) CB; XSTAGE(4, 1); CB;
    WAITV(12); WCONV(2, Wa) LGKM0; BAR; SB0; XGRP(2, 2); BAR; WLOAD(4, Wa) CB; XSTAGE(5, 2); CB;
    WAITV(12); WCONV(3, Wb) LGKM0; BAR; SB0; XGRP(3, 0); BAR; WLOAD(5, Wb) CB; XSTAGE(6, 0); CB;
    WAITV(12); WCONV(4, Wa) LGKM0; BAR; SB0; XGRP(4, 1); BAR; WLOAD(6, Wa) CB; XSTAGE(7, 1); CB;
    WAITV(12); WCONV(5, Wb) LGKM0; BAR; SB0; XGRP(5, 2); BAR; WLOAD(7, Wb) CB;
    WAITV(8);  WCONV(6, Wa) LGKM0; BAR; SB0; XGRP(6, 0); BAR;
    WAITV(0);  WCONV(7, Wb) LGKM0; BAR; SB0; XGRP(7, 1);

#undef XGRP
#undef XSTAGE
#undef WCONV
#undef WLOAD
#undef CB
#undef BAR
#undef SB0
#undef WAITV
#undef LGKM0

    // ---- routing (all fp32, per pixel), f = t*16 + q*4 + r ----
    // iter 0: v0[f] = 0.5*sum_g con ; beta1[g] = sum_f v0*con
    float v0[4][4];
    #pragma unroll
    for (int t = 0; t < 4; ++t)
        #pragma unroll
        for (int r = 0; r < 4; ++r) {
            float s = 0.f;
            #pragma unroll
            for (int g = 0; g < NG; ++g) s += acc[g][t][r];
            v0[t][r] = 0.5f * s;
        }

    float beta[NG], alpha[NG];
    #pragma unroll
    for (int g = 0; g < NG; ++g) {
        float s = 0.f;
        #pragma unroll
        for (int t = 0; t < 4; ++t)
            #pragma unroll
            for (int r = 0; r < 4; ++r)
                s += v0[t][r] * acc[g][t][r];
        s += __shfl_xor(s, 16);   // close f-sum across the 4 q-lanes
        s += __shfl_xor(s, 32);
        beta[g]  = s;
        alpha[g] = sigmoidf_fast(s);
    }

    // iter 1: v1[f] = sum_g alpha*con ; beta2 = beta1 + sum_f v1*con
    #pragma unroll
    for (int t = 0; t < 4; ++t)
        #pragma unroll
        for (int r = 0; r < 4; ++r) {
            float s = 0.f;
            #pragma unroll
            for (int g = 0; g < NG; ++g) s += alpha[g] * acc[g][t][r];
            v0[t][r] = s;  // reuse as v1
        }
    #pragma unroll
    for (int g = 0; g < NG; ++g) {
        float s = 0.f;
        #pragma unroll
        for (int t = 0; t < 4; ++t)
            #pragma unroll
            for (int r = 0; r < 4; ++r)
                s += v0[t][r] * acc[g][t][r];
        s += __shfl_xor(s, 16);
        s += __shfl_xor(s, 32);
        beta[g] += s;
        alpha[g] = sigmoidf_fast(beta[g]);
    }

    // iter 2: out[f] = sum_g alpha2*con + bias[f]
    #pragma unroll
    for (int t = 0; t < 4; ++t)
        #pragma unroll
        for (int r = 0; r < 4; ++r) {
            int f = t * 16 + q * 4 + r;
            float s = bias[f];
            #pragma unroll
            for (int g = 0; g < NG; ++g) s += alpha[g] * acc[g][t][r];
            out[((size_t)(b * NFO + f)) * HW + p0 + pw] = s;
        }
}

extern "C" void kernel_launch(void* const* d_in, const int* in_sizes, int n_in,
                              void* d_out, int out_size, void* d_ws, size_t ws_size,
                              hipStream_t stream) {
    const float* x    = (const float*)d_in[0];
    const float* w    = (const float*)d_in[1];
    const float* bias = (const float*)d_in[2];
    float* out = (float*)d_out;
    (void)d_ws; (void)ws_size;   // workspace unused

    routing_kernel<<<1024, 256, 0, stream>>>(x, w, bias, out);
}